// Round 8
// baseline (319.020 us; speedup 1.0000x reference)
//
#include <hip/hip_runtime.h>

#define CIN 64
#define COUT 64
#define BATCH 32
#define KTOT 576            // CIN * 9
#define NPOS 1024
#define KQ 144              // K per wave (4-way K-split)

// halo-padded transposed input: xT[i][34][34][b]
__device__ float g_xT[CIN * 34 * 34 * BATCH];

// Coalesced transpose repack: one block per (i, hh). Reads x rows (lanes over
// w, 128 B segments), transposes through LDS, writes g_xT rows (lanes over b,
// 128 B segments). Halo rows/cols written as zeros.
__global__ __launch_bounds__(256) void repack_kernel(const float* __restrict__ x) {
    __shared__ float tile[32 * 33];        // [b][w], pad 33 -> conflict-free
    const int i   = blockIdx.x;            // 0..63
    const int hh  = blockIdx.y;            // 0..33
    const int tid = threadIdx.x;

    float* dst = &g_xT[((i * 34 + hh) * 34) * BATCH];

    if (hh == 0 || hh == 33) {             // halo row: all zeros (34*32 floats)
        for (int idx = tid; idx < 34 * BATCH; idx += 256) dst[idx] = 0.f;
        return;
    }
    const int hs = hh - 1;
#pragma unroll
    for (int bb = 0; bb < 4; ++bb) {       // read 8 b-rows per pass
        int b = bb * 8 + (tid >> 5);
        int w = tid & 31;
        tile[b * 33 + w] = x[(b << 16) + (i << 10) + (hs << 5) + w];
    }
    __syncthreads();
#pragma unroll
    for (int q = 0; q < 5; ++q) {          // write 8 ww-rows per pass (34 total)
        int ww = q * 8 + (tid >> 5);
        if (ww < 34) {
            int b = tid & 31;
            float v = (ww == 0 || ww == 33) ? 0.f : tile[b * 33 + (ww - 1)];
            dst[ww * BATCH + b] = v;
        }
    }
}

// Block = (position p, cout-half oh), grid 2048, 256 threads = 4 waves.
// P panel [576 k][32 b] staged once in LDS (72 KB, coalesced, 64x reuse);
// W (zero reuse) streamed DIRECTLY to registers: per lane 4 contiguous
// 576-B row streams with immediate offsets, no waits -> the compiler can
// keep tens of independent float4 loads in flight per lane (the MLP that
// every staged variant in rounds 0-7 lacked; all pinned at ~1 TB/s with
// ~2-4 KB/wave outstanding). launch_bounds(256,2) allows up to 256 VGPR
// so load-ahead depth is the compiler's choice -> no forced spill (r6 bug).
// Wave wv owns K-quarter [wv*144, wv*144+144); acc[4 oc][4 bb] per lane;
// 4-way LDS tree reduction in the epilogue (r5's proven pattern).
__global__ __launch_bounds__(256, 2) void local2d_kernel(
    const float* __restrict__ weight,
    const float* __restrict__ bias,
    float* __restrict__ out)
{
    __shared__ __align__(16) float Pl[4 * KQ * 32];    // 73728 B

    const int tid = threadIdx.x;
    const int wv  = tid >> 6;              // wave 0..3 (K-quarter)
    const int l   = tid & 63;
    const int og  = l & 7;                 // o-sub:   o = oc*8 + og
    const int bg  = l >> 3;                // b-group: b = bg*4 + bb

    // XCD swizzle (r4 proven): xcd owns whole output rows; the two oh-halves
    // of a position are dispatch-adjacent -> g_xT L2 reuse.
    int bid = blockIdx.x;
    int xcd = bid & 7;
    int t   = bid >> 3;                    // 0..255
    int oh  = t & 1;                       // cout half
    int tt  = t >> 1;                      // 0..127
    int y   = ((tt >> 5) << 3) | xcd;
    int xw  = tt & 31;
    int p   = (y << 5) | xw;               // position = y*32 + x

    // ---- stage P panel: 576 k x 32 b = 72 KB, 18 passes x 256 thr x 16 B ----
    // slot = q*256 + tid -> k = q*32 + (tid>>3), b-quad = tid&7; 8 consecutive
    // lanes = 128 B contiguous in g_xT; LDS dst linear (conflict-free b128).
    for (int q = 0; q < 18; ++q) {
        int k  = (q << 5) + (tid >> 3);
        int i  = k / 9;
        int r  = k - i * 9;
        int kh = r / 3;
        int kw = r - kh * 3;
        const float* ps =
            &g_xT[((((i * 34) + y + kh) * 34 + xw + kw) << 5) + ((tid & 7) << 2)];
        *(float4*)(&Pl[((q << 8) + tid) << 2]) = *(const float4*)ps;
    }
    __syncthreads();

    const int kbase = wv * KQ;
    // 4 per-lane W row streams (o = oc*8 + og), each 144 k = 576 B contiguous
    const float* w0 = weight + ((long)p * COUT + (oh << 5) + 0  + og) * KTOT + kbase;
    const float* w1 = w0 + 8 * KTOT;
    const float* w2 = w0 + 16 * KTOT;
    const float* w3 = w0 + 24 * KTOT;
    // P base for this wave+lane: broadcast over og, bg-quads span 128 B
    const float* pb = Pl + wv * (KQ * 32) + (bg << 2);

    float acc[4][4];
#pragma unroll
    for (int a = 0; a < 4; ++a)
#pragma unroll
        for (int c = 0; c < 4; ++c) acc[a][c] = 0.f;

    // 3 outer x 12 unrolled k-quads: all offsets immediates; 96 independent
    // loads per outer iter for the scheduler to hoist.
    for (int u = 0; u < 3; ++u) {
#pragma unroll
        for (int s = 0; s < 12; ++s) {
            float4 pr[4];
#pragma unroll
            for (int j = 0; j < 4; ++j)
                pr[j] = *(const float4*)(pb + (((s << 2) + j) << 5));
            float4 wq[4];
            wq[0] = *(const float4*)(w0 + (s << 2));
            wq[1] = *(const float4*)(w1 + (s << 2));
            wq[2] = *(const float4*)(w2 + (s << 2));
            wq[3] = *(const float4*)(w3 + (s << 2));
            const float* prf = (const float*)pr;
#pragma unroll
            for (int oc = 0; oc < 4; ++oc)
#pragma unroll
                for (int bb = 0; bb < 4; ++bb) {
                    float a = acc[oc][bb];
                    a = fmaf(wq[oc].x, prf[0 + bb],  a);
                    a = fmaf(wq[oc].y, prf[4 + bb],  a);
                    a = fmaf(wq[oc].z, prf[8 + bb],  a);
                    a = fmaf(wq[oc].w, prf[12 + bb], a);
                    acc[oc][bb] = a;
                }
        }
        w0 += 48; w1 += 48; w2 += 48; w3 += 48;
        pb += 48 * 32;
    }

    // ---- 4-way cross-wave reduction (reuse P region; 3 slots x 32 x 36) ----
    __syncthreads();                       // all waves done reading Pl
    if (wv != 0) {
        float* R = &Pl[(wv - 1) * 1152];   // stride 36: 16B-aligned, spread
#pragma unroll
        for (int oc = 0; oc < 4; ++oc) {
            int o = (oc << 3) + og;
            *(float4*)(&R[o * 36 + (bg << 2)]) =
                make_float4(acc[oc][0], acc[oc][1], acc[oc][2], acc[oc][3]);
        }
    }
    __syncthreads();
    if (wv == 0) {
#pragma unroll
        for (int oc = 0; oc < 4; ++oc) {
            int o  = (oc << 3) + og;
            int of = (oh << 5) + o;        // global cout
            float s0 = acc[oc][0], s1 = acc[oc][1], s2 = acc[oc][2], s3 = acc[oc][3];
#pragma unroll
            for (int s = 0; s < 3; ++s) {
                float4 r = *(const float4*)(&Pl[s * 1152 + o * 36 + (bg << 2)]);
                s0 += r.x; s1 += r.y; s2 += r.z; s3 += r.w;
            }
            float bv = bias[(of << 10) + p];
            int b0 = bg << 2;
            out[((b0 + 0) << 16) + (of << 10) + p] = s0 + bv;
            out[((b0 + 1) << 16) + (of << 10) + p] = s1 + bv;
            out[((b0 + 2) << 16) + (of << 10) + p] = s2 + bv;
            out[((b0 + 3) << 16) + (of << 10) + p] = s3 + bv;
        }
    }
}

extern "C" void kernel_launch(void* const* d_in, const int* in_sizes, int n_in,
                              void* d_out, int out_size, void* d_ws, size_t ws_size,
                              hipStream_t stream) {
    const float* x      = (const float*)d_in[0];
    const float* weight = (const float*)d_in[1];
    const float* bias   = (const float*)d_in[2];
    float* out          = (float*)d_out;

    hipLaunchKernelGGL(repack_kernel, dim3(CIN, 34), dim3(256), 0, stream, x);
    hipLaunchKernelGGL(local2d_kernel, dim3(2 * NPOS), dim3(256), 0, stream,
                       weight, bias, out);
}